// Round 1
// baseline (6434.238 us; speedup 1.0000x reference)
//
#include <hip/hip_runtime.h>

#define B_ 16
#define S_ 2048
#define F_ 512
#define U_ 512
#define NROWS (B_ * S_)          // 32768
#define QB 16                    // queries per attention block
#define NQB (S_ / QB)            // 128

// ---------------------------------------------------------------------------
// Kernel 1: QKV projection GEMM.  C[M,N] = X[M,K] @ W[K,N], M=32768, N=K=512.
// blockIdx.z selects W_q / W_k / W_v; output goes to ws at z*M*N.
// 64x64 tile, BK=32, 256 threads, 4x4 microtile, fp32.
// ---------------------------------------------------------------------------
__global__ __launch_bounds__(256) void qkv_gemm(
    const float* __restrict__ X,
    const float* __restrict__ Wq,
    const float* __restrict__ Wk,
    const float* __restrict__ Wv,
    float* __restrict__ ws)
{
    const int z = blockIdx.z;
    const float* __restrict__ W = (z == 0) ? Wq : (z == 1) ? Wk : Wv;
    float* __restrict__ out = ws + (size_t)z * NROWS * U_;

    const int bm = blockIdx.x * 64;
    const int bn = blockIdx.y * 64;
    const int t  = threadIdx.x;
    const int tm = t >> 4;    // 0..15
    const int tn = t & 15;    // 0..15

    __shared__ float Xs[32][68];    // transposed: Xs[k][m]
    __shared__ float Wsh[32][68];   // Wsh[k][n]

    float acc[4][4];
    #pragma unroll
    for (int i = 0; i < 4; ++i)
        #pragma unroll
        for (int j = 0; j < 4; ++j) acc[i][j] = 0.f;

    for (int k0 = 0; k0 < F_; k0 += 32) {
        // stage X tile 64x32 (store transposed)
        #pragma unroll
        for (int l = t; l < 512; l += 256) {
            const int m  = l >> 3;
            const int f4 = (l & 7) << 2;
            const float4 v = *(const float4*)&X[(size_t)(bm + m) * F_ + k0 + f4];
            Xs[f4 + 0][m] = v.x;
            Xs[f4 + 1][m] = v.y;
            Xs[f4 + 2][m] = v.z;
            Xs[f4 + 3][m] = v.w;
        }
        // stage W tile 32x64
        #pragma unroll
        for (int l = t; l < 512; l += 256) {
            const int kk = l >> 4;
            const int n4 = (l & 15) << 2;
            *(float4*)&Wsh[kk][n4] =
                *(const float4*)&W[(size_t)(k0 + kk) * U_ + bn + n4];
        }
        __syncthreads();
        #pragma unroll
        for (int kk = 0; kk < 32; ++kk) {
            const float4 a = *(const float4*)&Xs[kk][tm * 4];
            const float4 b = *(const float4*)&Wsh[kk][tn * 4];
            acc[0][0] += a.x * b.x; acc[0][1] += a.x * b.y; acc[0][2] += a.x * b.z; acc[0][3] += a.x * b.w;
            acc[1][0] += a.y * b.x; acc[1][1] += a.y * b.y; acc[1][2] += a.y * b.z; acc[1][3] += a.y * b.w;
            acc[2][0] += a.z * b.x; acc[2][1] += a.z * b.y; acc[2][2] += a.z * b.z; acc[2][3] += a.z * b.w;
            acc[3][0] += a.w * b.x; acc[3][1] += a.w * b.y; acc[3][2] += a.w * b.z; acc[3][3] += a.w * b.w;
        }
        __syncthreads();
    }

    #pragma unroll
    for (int i = 0; i < 4; ++i) {
        float4 v;
        v.x = acc[i][0]; v.y = acc[i][1]; v.z = acc[i][2]; v.w = acc[i][3];
        *(float4*)&out[(size_t)(bm + tm * 4 + i) * U_ + bn + tn * 4] = v;
    }
}

// ---------------------------------------------------------------------------
// Kernel 2: flash-style attention.  Block = (qb, b), 256 threads.
// QB=16 query rows, key blocks of 64, online softmax, context in registers.
// Each thread: qi = t&15 (query row), ug = t>>4 (owns u columns ug*32..+31).
// Emits partial[b][qb][u] = sum over the 16 query rows of context.
// ---------------------------------------------------------------------------
__global__ __launch_bounds__(256) void attn_flash(
    const float* __restrict__ ws_qkv,
    float* __restrict__ partial)
{
    const float* __restrict__ Q = ws_qkv;
    const float* __restrict__ K = ws_qkv + (size_t)NROWS * U_;
    const float* __restrict__ V = ws_qkv + 2ull * NROWS * U_;

    const int qb = blockIdx.x;   // 0..127
    const int b  = blockIdx.y;   // 0..15
    const int q0 = qb * QB;
    const int t  = threadIdx.x;
    const int qi = t & 15;
    const int ug = t >> 4;       // 0..15
    const int u0 = ug * 32;

    __shared__ float Qs[16][516];
    __shared__ float KVs[64 * 132];   // union: Ks[64][132] / Vs[16][516] / Cs[16][516]
    __shared__ float Ss[16][68];

    // stage Q tile [16][512]
    for (int l = t; l < 2048; l += 256) {
        const int r  = l >> 7;
        const int c4 = (l & 127) << 2;
        *(float4*)&Qs[r][c4] =
            *(const float4*)&Q[(size_t)(b * S_ + q0 + r) * U_ + c4];
    }

    float C[32];
    #pragma unroll
    for (int i = 0; i < 32; ++i) C[i] = 0.f;
    float m_i = -1e30f, l_i = 0.f;
    const float scale = 0.044194173824159216f;   // 1/sqrt(512)

    for (int kb = 0; kb < S_ / 64; ++kb) {
        float s4[4] = {0.f, 0.f, 0.f, 0.f};

        // ---- QK^T: accumulate over 4 feature chunks of 128 ----
        for (int fc = 0; fc < 4; ++fc) {
            __syncthreads();   // (a) previous users of KVs done
            for (int l = t; l < 2048; l += 256) {
                const int r  = l >> 5;
                const int c4 = (l & 31) << 2;
                *(float4*)&KVs[r * 132 + c4] =
                    *(const float4*)&K[(size_t)(b * S_ + kb * 64 + r) * U_ + fc * 128 + c4];
            }
            __syncthreads();   // (b)
            #pragma unroll 8
            for (int f = 0; f < 128; f += 4) {
                const float4 q4 = *(const float4*)&Qs[qi][fc * 128 + f];
                #pragma unroll
                for (int j = 0; j < 4; ++j) {
                    const float4 k4 = *(const float4*)&KVs[(ug * 4 + j) * 132 + f];
                    s4[j] += q4.x * k4.x + q4.y * k4.y + q4.z * k4.z + q4.w * k4.w;
                }
            }
        }
        __syncthreads();       // (c)

        // ---- online softmax ----
        #pragma unroll
        for (int j = 0; j < 4; ++j) Ss[qi][ug * 4 + j] = s4[j] * scale;
        __syncthreads();       // (d)
        float m_blk = -1e30f;
        #pragma unroll 16
        for (int k = 0; k < 64; ++k) m_blk = fmaxf(m_blk, Ss[qi][k]);
        const float m_new = fmaxf(m_i, m_blk);
        const float alpha = __expf(m_i - m_new);
        m_i = m_new;
        l_i *= alpha;
        #pragma unroll
        for (int i = 0; i < 32; ++i) C[i] *= alpha;
        __syncthreads();       // (e) raw-score reads done
        #pragma unroll
        for (int j = 0; j < 4; ++j)
            Ss[qi][ug * 4 + j] = __expf(s4[j] * scale - m_new);
        __syncthreads();       // (f) p visible

        // ---- PV: 4 sub-chunks of 16 keys, V staged full-width ----
        float l_add = 0.f;
        for (int sub = 0; sub < 4; ++sub) {
            for (int l = t; l < 2048; l += 256) {
                const int r  = l >> 7;
                const int c4 = (l & 127) << 2;
                *(float4*)&KVs[r * 516 + c4] =
                    *(const float4*)&V[(size_t)(b * S_ + kb * 64 + sub * 16 + r) * U_ + c4];
            }
            __syncthreads();   // (g)
            #pragma unroll 4
            for (int kk = 0; kk < 16; ++kk) {
                const float p = Ss[qi][sub * 16 + kk];
                l_add += p;
                #pragma unroll
                for (int j8 = 0; j8 < 8; ++j8) {
                    const float4 v4 = *(const float4*)&KVs[kk * 516 + u0 + j8 * 4];
                    C[j8 * 4 + 0] += p * v4.x;
                    C[j8 * 4 + 1] += p * v4.y;
                    C[j8 * 4 + 2] += p * v4.z;
                    C[j8 * 4 + 3] += p * v4.w;
                }
            }
            __syncthreads();   // (h)
        }
        l_i += l_add;
    }

    // ---- normalize + partial sum over the 16 query rows ----
    const float inv_l = 1.0f / l_i;
    #pragma unroll
    for (int i = 0; i < 32; ++i)
        KVs[qi * 516 + u0 + i] = C[i] * inv_l;    // Cs[16][516]
    __syncthreads();
    for (int u = t; u < 512; u += 256) {
        float s = 0.f;
        #pragma unroll 4
        for (int q = 0; q < 16; ++q) s += KVs[q * 516 + u];
        partial[(size_t)(b * NQB + qb) * U_ + u] = s;
    }
}

// ---------------------------------------------------------------------------
// Kernel 3: reduce partials -> mean over S.
// ---------------------------------------------------------------------------
__global__ __launch_bounds__(256) void reduce_mean(
    const float* __restrict__ partial,
    float* __restrict__ out)
{
    const int b = blockIdx.x;
    for (int u = threadIdx.x; u < U_; u += 256) {
        float s = 0.f;
        for (int p = 0; p < NQB; ++p)
            s += partial[(size_t)(b * NQB + p) * U_ + u];
        out[b * U_ + u] = s * (1.0f / (float)S_);
    }
}

extern "C" void kernel_launch(void* const* d_in, const int* in_sizes, int n_in,
                              void* d_out, int out_size, void* d_ws, size_t ws_size,
                              hipStream_t stream)
{
    const float* x  = (const float*)d_in[0];
    const float* Wq = (const float*)d_in[1];
    const float* Wk = (const float*)d_in[2];
    const float* Wv = (const float*)d_in[3];
    float* out = (float*)d_out;
    float* ws  = (float*)d_ws;

    // ws layout (floats): Q[32768*512] | K | V | partial[16*128*512]
    const size_t need = (3ull * NROWS * U_ + (size_t)B_ * NQB * U_) * sizeof(float);
    if (ws_size < need) return;   // loud failure: validation will catch it

    float* partial = ws + 3ull * NROWS * U_;

    // 1) QKV projections
    dim3 g1(NROWS / 64, U_ / 64, 3);
    qkv_gemm<<<g1, 256, 0, stream>>>(x, Wq, Wk, Wv, ws);

    // 2) flash attention -> per-block partial query sums
    dim3 g2(NQB, B_);
    attn_flash<<<g2, 256, 0, stream>>>(ws, partial);

    // 3) mean over queries
    reduce_mean<<<B_, 256, 0, stream>>>(partial, out);
}

// Round 2
// 728.410 us; speedup vs baseline: 8.8333x; 8.8333x over previous
//
#include <hip/hip_runtime.h>

typedef short bf16x8 __attribute__((ext_vector_type(8)));
typedef float f32x4 __attribute__((ext_vector_type(4)));
typedef unsigned short us4 __attribute__((ext_vector_type(4)));

#define B_ 16
#define S_ 2048
#define F_ 512
#define U_ 512
#define NROWS (B_ * S_)          // 32768

#define MFMA(a, b, c) __builtin_amdgcn_mfma_f32_16x16x32_bf16((a), (b), (c), 0, 0, 0)

__device__ __forceinline__ unsigned short f2b(float f) {
    unsigned u = __builtin_bit_cast(unsigned, f);
    return (unsigned short)((u + 0x7FFFu + ((u >> 16) & 1u)) >> 16);
}

// ---------------------------------------------------------------------------
// x fp32 -> bf16 row-major [32768][512]
// ---------------------------------------------------------------------------
__global__ __launch_bounds__(256) void conv_x(const float* __restrict__ x,
                                              unsigned short* __restrict__ xb)
{
    const size_t n8 = (size_t)NROWS * F_ / 8;
    const size_t stride = (size_t)gridDim.x * 256;
    for (size_t i = (size_t)blockIdx.x * 256 + threadIdx.x; i < n8; i += stride) {
        const float4 a = ((const float4*)x)[i * 2];
        const float4 b = ((const float4*)x)[i * 2 + 1];
        us4 lo, hi;
        lo.x = f2b(a.x); lo.y = f2b(a.y); lo.z = f2b(a.z); lo.w = f2b(a.w);
        hi.x = f2b(b.x); hi.y = f2b(b.y); hi.z = f2b(b.z); hi.w = f2b(b.w);
        ((us4*)xb)[i * 2]     = lo;
        ((us4*)xb)[i * 2 + 1] = hi;
    }
}

// ---------------------------------------------------------------------------
// W [k][n] fp32 -> Wt [z][n][k] bf16 (transposed)
// ---------------------------------------------------------------------------
__global__ __launch_bounds__(256) void conv_w(const float* __restrict__ Wq,
                                              const float* __restrict__ Wk,
                                              const float* __restrict__ Wv,
                                              unsigned short* __restrict__ Wt)
{
    const float* W = (blockIdx.z == 0) ? Wq : (blockIdx.z == 1) ? Wk : Wv;
    unsigned short* out = Wt + (size_t)blockIdx.z * F_ * U_;
    __shared__ float tile[32][33];
    const int k0 = blockIdx.x * 32, n0 = blockIdx.y * 32;
    const int r = threadIdx.x >> 5, c = threadIdx.x & 31;
    #pragma unroll
    for (int p = 0; p < 4; ++p)
        tile[p * 8 + r][c] = W[(size_t)(k0 + p * 8 + r) * U_ + n0 + c];
    __syncthreads();
    #pragma unroll
    for (int p = 0; p < 4; ++p)
        out[(size_t)(n0 + p * 8 + r) * F_ + k0 + c] = f2b(tile[c][p * 8 + r]);
}

// ---------------------------------------------------------------------------
// QKV GEMM, bf16 MFMA 16x16x32.  C[M=32768][N=512] per z.
// Tile 128x64, 4 waves (wave w: rows 32w..32w+31), BK=32.
// z=0 -> Qb row-major, z=1 -> Kb row-major, z=2 -> Vt transposed [b][u][s].
// ---------------------------------------------------------------------------
__global__ __launch_bounds__(256) void qkv_gemm(
    const unsigned short* __restrict__ xb,
    const unsigned short* __restrict__ Wt,
    unsigned short* __restrict__ Qb,
    unsigned short* __restrict__ Kb,
    unsigned short* __restrict__ Vt)
{
    __shared__ char smem[128 * 65 * 4];                 // 33280 B
    unsigned short* Xs = (unsigned short*)smem;         // [128][32]
    unsigned short* Ws = Xs + 128 * 32;                 // [64][32]
    float* Cs = (float*)smem;                           // [128][65]

    const int z = blockIdx.z;
    const unsigned short* Wz = Wt + (size_t)z * F_ * U_;
    const int bm = blockIdx.x * 128;
    const int bn = blockIdx.y * 64;
    const int t = threadIdx.x;
    const int w = t >> 6, l = t & 63, lr = l & 15, lg = l >> 4;

    f32x4 acc[2][4];
    #pragma unroll
    for (int mt = 0; mt < 2; ++mt)
        #pragma unroll
        for (int nt = 0; nt < 4; ++nt)
            acc[mt][nt] = (f32x4){0.f, 0.f, 0.f, 0.f};

    for (int kc = 0; kc < 16; ++kc) {
        const int k0 = kc * 32;
        __syncthreads();
        #pragma unroll
        for (int p = 0; p < 2; ++p) {
            const int idx = p * 256 + t;
            const int row = idx >> 2, off = (idx & 3) * 8;
            *(bf16x8*)&Xs[row * 32 + off] =
                *(const bf16x8*)&xb[(size_t)(bm + row) * F_ + k0 + off];
        }
        {
            const int row = t >> 2, off = (t & 3) * 8;
            *(bf16x8*)&Ws[row * 32 + off] =
                *(const bf16x8*)&Wz[(size_t)(bn + row) * F_ + k0 + off];
        }
        __syncthreads();
        const bf16x8 a0 = *(const bf16x8*)&Xs[(w * 32 + lr) * 32 + lg * 8];
        const bf16x8 a1 = *(const bf16x8*)&Xs[(w * 32 + 16 + lr) * 32 + lg * 8];
        #pragma unroll
        for (int nt = 0; nt < 4; ++nt) {
            const bf16x8 bb = *(const bf16x8*)&Ws[(nt * 16 + lr) * 32 + lg * 8];
            acc[0][nt] = MFMA(a0, bb, acc[0][nt]);
            acc[1][nt] = MFMA(a1, bb, acc[1][nt]);
        }
    }
    __syncthreads();
    #pragma unroll
    for (int mt = 0; mt < 2; ++mt)
        #pragma unroll
        for (int nt = 0; nt < 4; ++nt)
            #pragma unroll
            for (int j = 0; j < 4; ++j)
                Cs[(w * 32 + mt * 16 + lg * 4 + j) * 65 + nt * 16 + lr] = acc[mt][nt][j];
    __syncthreads();

    if (z < 2) {
        unsigned short* out = (z == 0) ? Qb : Kb;
        const int row = t >> 1, half = t & 1;
        unsigned short tmp[32];
        #pragma unroll
        for (int i = 0; i < 32; ++i) tmp[i] = f2b(Cs[row * 65 + half * 32 + i]);
        #pragma unroll
        for (int v = 0; v < 4; ++v)
            *(bf16x8*)&out[(size_t)(bm + row) * U_ + bn + half * 32 + v * 8] =
                *(bf16x8*)&tmp[v * 8];
    } else {
        const int c = t >> 2, s0 = (t & 3) * 32;
        const int b = bm >> 11, sbase = (bm & 2047) + s0;
        unsigned short tmp[32];
        #pragma unroll
        for (int i = 0; i < 32; ++i) tmp[i] = f2b(Cs[(s0 + i) * 65 + c]);
        #pragma unroll
        for (int v = 0; v < 4; ++v)
            *(bf16x8*)&Vt[((size_t)(b * U_ + bn + c)) * S_ + sbase + v * 8] =
                *(bf16x8*)&tmp[v * 8];
    }
}

// ---------------------------------------------------------------------------
// Flash attention with MFMA.  Block = (qblk, b), 256 threads = 4 waves.
// Wave w owns 16 queries (qblk*64 + 16w + lr).  32 keys per iteration.
// QK^T computed swapped: S^T = mfma(K, Q)  ->  lane holds col=query, rows=keys.
// P transposed to MFMA-A layout through small LDS buffer (per-wave private).
// PV: ctx[q][u] = mfma(P, Vt), Vt staged [u][key] so B-frag is row-contiguous.
// Output: per-block partial sum over its 64 queries of normalized context.
// ---------------------------------------------------------------------------
__global__ __launch_bounds__(256, 2) void attn_mfma(
    const unsigned short* __restrict__ Qb,
    const unsigned short* __restrict__ Kb,
    const unsigned short* __restrict__ Vt,
    float* __restrict__ partial)
{
    __shared__ unsigned short Ks[32 * 512];      // [32 keys][512 f]   32 KB
    __shared__ unsigned short Vs[512 * 32];      // [512 u][32 keys]   32 KB
    __shared__ unsigned short Ps[64 * 48];       // [64 q][48 keys]     6 KB

    const int qblk = blockIdx.x;        // 0..31
    const int b    = blockIdx.y;        // 0..15
    const int t = threadIdx.x;
    const int w = t >> 6, l = t & 63, lr = l & 15, lg = l >> 4;
    const float scale = 0.044194173824159216f;   // 1/sqrt(512)

    // hoist Q fragments into registers: 16 chunks x 8 bf16
    bf16x8 q[16];
    {
        const unsigned short* qg =
            Qb + (size_t)(b * S_ + qblk * 64 + w * 16 + lr) * U_ + lg * 8;
        #pragma unroll
        for (int kc = 0; kc < 16; ++kc)
            q[kc] = *(const bf16x8*)(qg + kc * 32);
    }

    f32x4 ctx[32];
    #pragma unroll
    for (int nt = 0; nt < 32; ++nt) ctx[nt] = (f32x4){0.f, 0.f, 0.f, 0.f};
    float m_i = -1e30f, l_i = 0.f;

    for (int kb = 0; kb < S_ / 32; ++kb) {
        __syncthreads();   // prev iteration done reading Ks/Vs
        // stage K [32][512]
        {
            const unsigned short* kg = Kb + (size_t)(b * S_ + kb * 32) * U_;
            #pragma unroll
            for (int p = 0; p < 8; ++p) {
                const int idx = p * 256 + t;          // 2048 chunks of 8
                const int row = idx >> 6, off = (idx & 63) * 8;
                *(bf16x8*)&Ks[row * 512 + off] = *(const bf16x8*)&kg[row * 512 + off];
            }
            // stage Vt chunk [512][32]
            const unsigned short* vg = Vt + (size_t)b * U_ * S_ + kb * 32;
            #pragma unroll
            for (int p = 0; p < 8; ++p) {
                const int idx = p * 256 + t;
                const int row = idx >> 2, off = (idx & 3) * 8;
                *(bf16x8*)&Vs[row * 32 + off] = *(const bf16x8*)&vg[(size_t)row * S_ + off];
            }
        }
        __syncthreads();

        // ---- QK^T (swapped): S^T[key][q], 2 key tiles ----
        f32x4 s0 = (f32x4){0.f, 0.f, 0.f, 0.f};
        f32x4 s1 = (f32x4){0.f, 0.f, 0.f, 0.f};
        #pragma unroll
        for (int kc = 0; kc < 16; ++kc) {
            const bf16x8 k0 = *(const bf16x8*)&Ks[lr * 512 + kc * 32 + lg * 8];
            const bf16x8 k1 = *(const bf16x8*)&Ks[(16 + lr) * 512 + kc * 32 + lg * 8];
            s0 = MFMA(k0, q[kc], s0);
            s1 = MFMA(k1, q[kc], s1);
        }

        // ---- online softmax (per query = lane&15 column) ----
        float sc0[4], sc1[4];
        #pragma unroll
        for (int j = 0; j < 4; ++j) { sc0[j] = s0[j] * scale; sc1[j] = s1[j] * scale; }
        float mb = sc0[0];
        #pragma unroll
        for (int j = 1; j < 4; ++j) mb = fmaxf(mb, sc0[j]);
        #pragma unroll
        for (int j = 0; j < 4; ++j) mb = fmaxf(mb, sc1[j]);
        mb = fmaxf(mb, __shfl_xor(mb, 16));
        mb = fmaxf(mb, __shfl_xor(mb, 32));
        const float m_new = fmaxf(m_i, mb);
        const float alpha = __expf(m_i - m_new);
        float p0[4], p1[4];
        float ladd = 0.f;
        #pragma unroll
        for (int j = 0; j < 4; ++j) {
            p0[j] = __expf(sc0[j] - m_new);
            p1[j] = __expf(sc1[j] - m_new);
            ladd += p0[j] + p1[j];
        }
        ladd += __shfl_xor(ladd, 16);
        ladd += __shfl_xor(ladd, 32);
        l_i = l_i * alpha + ladd;
        m_i = m_new;

        // per-row alphas for context rescale (ctx rows = queries 4*lg+j)
        float arow[4];
        #pragma unroll
        for (int j = 0; j < 4; ++j)
            arow[j] = __shfl(alpha, (l & 48) | (lg * 4 + j));
        #pragma unroll
        for (int nt = 0; nt < 32; ++nt)
            #pragma unroll
            for (int j = 0; j < 4; ++j) ctx[nt][j] *= arow[j];

        // ---- write P (transpose via per-wave-private LDS rows) ----
        us4 w0, w1;
        w0.x = f2b(p0[0]); w0.y = f2b(p0[1]); w0.z = f2b(p0[2]); w0.w = f2b(p0[3]);
        w1.x = f2b(p1[0]); w1.y = f2b(p1[1]); w1.z = f2b(p1[2]); w1.w = f2b(p1[3]);
        *(us4*)&Ps[(w * 16 + lr) * 48 + lg * 4]      = w0;   // keys 4lg..4lg+3
        *(us4*)&Ps[(w * 16 + lr) * 48 + 16 + lg * 4] = w1;   // keys 16+4lg..
        const bf16x8 pf = *(const bf16x8*)&Ps[(w * 16 + lr) * 48 + lg * 8];

        // ---- PV: ctx[16q x 512u] += P[16q x 32k] @ V[32k x 512u] ----
        #pragma unroll
        for (int nt = 0; nt < 32; ++nt) {
            const bf16x8 vf = *(const bf16x8*)&Vs[(nt * 16 + lr) * 32 + lg * 8];
            ctx[nt] = MFMA(pf, vf, ctx[nt]);
        }
    }

    // ---- epilogue: normalize, sum the wave's 16 queries, combine waves ----
    const float inv = 1.f / l_i;
    float invr[4];
    #pragma unroll
    for (int j = 0; j < 4; ++j)
        invr[j] = __shfl(inv, (l & 48) | (lg * 4 + j));

    __syncthreads();                       // done with Ks; alias as SumBuf
    float* SumBuf = (float*)Ks;            // [4][512] fp32
    #pragma unroll
    for (int nt = 0; nt < 32; ++nt) {
        float s = ctx[nt][0] * invr[0] + ctx[nt][1] * invr[1]
                + ctx[nt][2] * invr[2] + ctx[nt][3] * invr[3];
        s += __shfl_xor(s, 16);
        s += __shfl_xor(s, 32);
        if (lg == 0) SumBuf[w * 512 + nt * 16 + lr] = s;
    }
    __syncthreads();
    for (int u = t; u < 512; u += 256) {
        const float s = SumBuf[u] + SumBuf[512 + u] + SumBuf[1024 + u] + SumBuf[1536 + u];
        partial[(size_t)(b * 32 + qblk) * U_ + u] = s;
    }
}

// ---------------------------------------------------------------------------
// partial [16][32][512] -> out [16][512], mean over S
// ---------------------------------------------------------------------------
__global__ __launch_bounds__(256) void reduce_mean(
    const float* __restrict__ partial, float* __restrict__ out)
{
    const int b = blockIdx.x;
    for (int u = threadIdx.x; u < U_; u += 256) {
        float s = 0.f;
        #pragma unroll 8
        for (int p = 0; p < 32; ++p)
            s += partial[(size_t)(b * 32 + p) * U_ + u];
        out[b * U_ + u] = s * (1.0f / (float)S_);
    }
}

extern "C" void kernel_launch(void* const* d_in, const int* in_sizes, int n_in,
                              void* d_out, int out_size, void* d_ws, size_t ws_size,
                              hipStream_t stream)
{
    const float* x  = (const float*)d_in[0];
    const float* Wq = (const float*)d_in[1];
    const float* Wk = (const float*)d_in[2];
    const float* Wv = (const float*)d_in[3];
    float* out = (float*)d_out;

    // ws layout (ushort units unless noted)
    unsigned short* ws = (unsigned short*)d_ws;
    const size_t XB_OFF = 0;                               // [32768][512] bf16
    const size_t WT_OFF = XB_OFF + (size_t)NROWS * F_;     // 3x[512][512] bf16
    const size_t QB_OFF = WT_OFF + 3ull * F_ * U_;
    const size_t KB_OFF = QB_OFF + (size_t)NROWS * U_;
    const size_t VT_OFF = KB_OFF + (size_t)NROWS * U_;
    const size_t END_USH = VT_OFF + (size_t)NROWS * U_;
    float* partial = (float*)(ws + END_USH);               // [16][32][512] fp32
    const size_t need = END_USH * 2 + (size_t)B_ * 32 * U_ * 4;
    if (ws_size < need) return;

    unsigned short* xb = ws + XB_OFF;
    unsigned short* Wt = ws + WT_OFF;
    unsigned short* Qb = ws + QB_OFF;
    unsigned short* Kb = ws + KB_OFF;
    unsigned short* Vt = ws + VT_OFF;

    conv_x<<<2048, 256, 0, stream>>>(x, xb);
    conv_w<<<dim3(16, 16, 3), 256, 0, stream>>>(Wq, Wk, Wv, Wt);
    qkv_gemm<<<dim3(NROWS / 128, U_ / 64, 3), 256, 0, stream>>>(xb, Wt, Qb, Kb, Vt);
    attn_mfma<<<dim3(32, 16), 256, 0, stream>>>(Qb, Kb, Vt, partial);
    reduce_mean<<<B_, 256, 0, stream>>>(partial, out);
}